// Round 3
// baseline (159.358 us; speedup 1.0000x reference)
//
#include <hip/hip_runtime.h>
#include <cstdint>
#include <cstddef>

using u16    = uint16_t;
using u16x4  = __attribute__((ext_vector_type(4))) uint16_t;
using u16x8  = __attribute__((ext_vector_type(8))) uint16_t;
using bf16x2 = __attribute__((ext_vector_type(2))) __bf16;
using bf16x8 = __attribute__((ext_vector_type(8))) __bf16;
using f32x4  = __attribute__((ext_vector_type(4))) float;
using f32x16 = __attribute__((ext_vector_type(16))) float;

// B=2, N=2048, C=768, H=12, D=64 ; M = B*N = 4096
// Inputs fp32; intermediates bf16; OUTPUT fp32.
__device__ __forceinline__ u16 f2b(float f) {
    union { float f; uint32_t u; } x; x.f = f;
    uint32_t r = x.u + 0x7FFFu + ((x.u >> 16) & 1u);
    return (u16)(r >> 16);
}
// hardware bf16 pack (RNE; fuses to v_cvt_pk_bf16_f32 on gfx950)
__device__ __forceinline__ uint32_t pk2(float a, float b) {
    bf16x2 t; t[0] = (__bf16)a; t[1] = (__bf16)b;
    return __builtin_bit_cast(uint32_t, t);
}
// 16B fragment from two 8B LDS reads (b64 ops allow strides ≡2 mod 4 dw)
__device__ __forceinline__ bf16x8 ld8(const u16* p) {
    union { u16x8 v; u16x4 h[2]; } r;
    r.h[0] = *(const u16x4*)p;
    r.h[1] = *(const u16x4*)(p + 4);
    return __builtin_bit_cast(bf16x8, r.v);
}
__device__ __forceinline__ u16x8 ld8u(const u16* p) {
    union { u16x8 v; u16x4 h[2]; } r;
    r.h[0] = *(const u16x4*)p;
    r.h[1] = *(const u16x4*)(p + 4);
    return r.v;
}
// V A-fragment read: keys {base+0..3, base+8..11} (sigma-permuted K-slots)
__device__ __forceinline__ bf16x8 ldvf(const u16* p) {
    union { u16x8 v; u16x4 h[2]; } r;
    r.h[0] = *(const u16x4*)p;
    r.h[1] = *(const u16x4*)(p + 8);
    return __builtin_bit_cast(bf16x8, r.v);
}
__device__ __forceinline__ void st8(u16* p, u16x8 v) {
    union { u16x8 v; u16x4 h[2]; } r; r.v = v;
    *(u16x4*)p       = r.h[0];
    *(u16x4*)(p + 4) = r.h[1];
}

// async global->LDS, 16B per lane, LDS dest = wave-uniform base + lane*16
__device__ __forceinline__ void load16_async(const u16* g, u16* lds_base) {
    __builtin_amdgcn_global_load_lds(
        (const __attribute__((address_space(1))) u16*)g,
        (__attribute__((address_space(3))) u16*)(uint32_t)(uintptr_t)lds_base,
        16, 0, 0);
}

// fp32 -> bf16 bulk converter for x, w_qkv, w_proj (counts in float4 units)
__global__ void conv_k(const float* __restrict__ x,  u16* __restrict__ xb,  int nx4,
                       const float* __restrict__ w1, u16* __restrict__ w1b, int n14,
                       const float* __restrict__ w2, u16* __restrict__ w2b, int n24)
{
    const int t   = blockIdx.x * blockDim.x + threadIdx.x;
    const int stp = gridDim.x * blockDim.x;
    for (int i = t; i < nx4; i += stp) {
        f32x4 v = ((const f32x4*)x)[i];
        u16x4 o;
        #pragma unroll
        for (int e = 0; e < 4; e++) o[e] = f2b(v[e]);
        ((u16x4*)xb)[i] = o;
    }
    for (int i = t; i < n14; i += stp) {
        f32x4 v = ((const f32x4*)w1)[i];
        u16x4 o;
        #pragma unroll
        for (int e = 0; e < 4; e++) o[e] = f2b(v[e]);
        ((u16x4*)w1b)[i] = o;
    }
    for (int i = t; i < n24; i += stp) {
        f32x4 v = ((const f32x4*)w2)[i];
        u16x4 o;
        #pragma unroll
        for (int e = 0; e < 4; e++) o[e] = f2b(v[e]);
        ((u16x4*)w2b)[i] = o;
    }
}

// QKV: C = A[4096,768] @ W[2304,768]^T + bias ; 128x128 tiles, m97 async staging.
__global__ __launch_bounds__(256, 3) void gemm_qkv(
    const u16* __restrict__ A, const u16* __restrict__ W,
    const float* __restrict__ bias,
    u16* __restrict__ O0, u16* __restrict__ O1, u16* __restrict__ O2)
{
    // K-loop: As [128*32] | Bs [128*32] (16 KB). Epilogue (V blocks): T [128][132] u16 (33.8 KB)
    __shared__ alignas(16) char smem[33792];
    u16* As = (u16*)smem;
    u16* Bs = (u16*)(smem + 8192);
    u16* T  = (u16*)smem;

    const int tid  = threadIdx.x;
    const int wid  = tid >> 6, lane = tid & 63;
    const int quad = lane >> 4, lc = lane & 15;
    const int row0 = blockIdx.x * 128, col0 = blockIdx.y * 128;
    const int wm   = (wid >> 1) * 64, wn = (wid & 1) * 64;

    const int srA = wid * 32 + (lane >> 2);
    const int scA = (lane & 3) * 8;

    f32x4 acc[4][4] = {};

    for (int k0 = 0; k0 < 768; k0 += 32) {
        __syncthreads();
        #pragma unroll
        for (int t = 0; t < 2; t++) {
            load16_async(&A[(row0 + srA + t*16) * 768 + k0 + scA], &As[wid*1024 + t*512]);
            load16_async(&W[(col0 + srA + t*16) * 768 + k0 + scA], &Bs[wid*1024 + t*512]);
        }
        __syncthreads();

        bf16x8 a[4], b[4];
        #pragma unroll
        for (int i = 0; i < 4; i++)
            a[i] = __builtin_bit_cast(bf16x8, *(const u16x8*)&As[(wm + i*16 + lc)*32 + quad*8]);
        #pragma unroll
        for (int j = 0; j < 4; j++)
            b[j] = __builtin_bit_cast(bf16x8, *(const u16x8*)&Bs[(wn + j*16 + lc)*32 + quad*8]);
        #pragma unroll
        for (int i = 0; i < 4; i++)
            #pragma unroll
            for (int j = 0; j < 4; j++)
                acc[i][j] = __builtin_amdgcn_mfma_f32_16x16x32_bf16(a[i], b[j], acc[i][j], 0, 0, 0);
    }

    if (col0 < 1536) {
        // Q / K blocks: direct store (entire block is one region)
        #pragma unroll
        for (int i = 0; i < 4; i++) {
            #pragma unroll
            for (int j = 0; j < 4; j++) {
                const int gc = col0 + wn + j*16 + lc;
                const float bv = bias[gc];
                #pragma unroll
                for (int r = 0; r < 4; r++) {
                    const int gr = row0 + wm + i*16 + quad*4 + r;
                    const u16 ob = f2b(acc[i][j][r] + bv);
                    if (gc < 768) O0[gr * 768 + gc] = ob;          // Q[b,n][h*64+d]
                    else          O1[gr * 768 + (gc - 768)] = ob;  // K[b,n][h*64+d]
                }
            }
        }
    } else {
        // V block: transpose via LDS, then coalesced stores to Vt[bh][d][n]
        __syncthreads();   // all K-loop LDS reads done before T overlay write
        #pragma unroll
        for (int j = 0; j < 4; j++) {
            const int cl = wn + j*16 + lc;               // local feature (d) col
            const float bv = bias[col0 + cl];
            #pragma unroll
            for (int i = 0; i < 4; i++) {
                uint2 w;
                w.x = pk2(acc[i][j][0] + bv, acc[i][j][1] + bv);
                w.y = pk2(acc[i][j][2] + bv, acc[i][j][3] + bv);
                *(uint2*)&T[cl*132 + wm + i*16 + quad*4] = w;   // 4 consecutive tokens
            }
        }
        __syncthreads();

        const int cl = tid >> 1;                          // local d col 0..127
        const int sg = (tid & 1) * 64;                    // token segment base
        const int c2 = (col0 - 1536) + cl;                // = h*64 + d
        const int hh = c2 >> 6, dd = c2 & 63;
        const int bb = row0 >> 11, nn0 = row0 & 2047;
        u16* dst = &O2[((size_t)((bb*12 + hh)*64 + dd))*2048 + nn0 + sg];
        #pragma unroll
        for (int k = 0; k < 8; k++)
            *(u16x8*)&dst[k*8] = ld8u(&T[cl*132 + sg + k*8]);
    }
}

// Proj: 64x64 tiles (768 blocks), m97 async staging. fp32 output + bias.
__global__ __launch_bounds__(256, 4) void gemm_proj(
    const u16* __restrict__ A, const u16* __restrict__ W,
    const float* __restrict__ bias, float* __restrict__ F0)
{
    __shared__ alignas(16) u16 As[64 * 32];
    __shared__ alignas(16) u16 Bs[64 * 32];
    const int tid  = threadIdx.x;
    const int wid  = tid >> 6, lane = tid & 63;
    const int quad = lane >> 4, lc = lane & 15;
    const int row0 = blockIdx.x * 64, col0 = blockIdx.y * 64;
    const int wm   = (wid >> 1) * 32, wn = (wid & 1) * 32;

    const int srA = wid * 16 + (lane >> 2);
    const int scA = (lane & 3) * 8;

    f32x4 acc[2][2] = {};

    for (int k0 = 0; k0 < 768; k0 += 32) {
        __syncthreads();
        load16_async(&A[(row0 + srA) * 768 + k0 + scA], &As[wid*512]);
        load16_async(&W[(col0 + srA) * 768 + k0 + scA], &Bs[wid*512]);
        __syncthreads();

        bf16x8 a[2], b[2];
        #pragma unroll
        for (int i = 0; i < 2; i++)
            a[i] = __builtin_bit_cast(bf16x8, *(const u16x8*)&As[(wm + i*16 + lc)*32 + quad*8]);
        #pragma unroll
        for (int j = 0; j < 2; j++)
            b[j] = __builtin_bit_cast(bf16x8, *(const u16x8*)&Bs[(wn + j*16 + lc)*32 + quad*8]);
        #pragma unroll
        for (int i = 0; i < 2; i++)
            #pragma unroll
            for (int j = 0; j < 2; j++)
                acc[i][j] = __builtin_amdgcn_mfma_f32_16x16x32_bf16(a[i], b[j], acc[i][j], 0, 0, 0);
    }

    #pragma unroll
    for (int i = 0; i < 2; i++)
        #pragma unroll
        for (int j = 0; j < 2; j++) {
            const int gc = col0 + wn + j*16 + lc;
            const float bv = bias[gc];
            #pragma unroll
            for (int r = 0; r < 4; r++) {
                const int gr = row0 + wm + i*16 + quad*4 + r;
                F0[gr * 768 + gc] = acc[i][j][r] + bv;
            }
        }
}

// Flash attention, R2 restructure: 32x32x16 MFMA + fully in-register P.
//   Block = 32 q, 128-key tiles, 4 waves x 32 keys. 1536 blocks.
//   QK^T: S^T = mfma32(K_frag, Q_frag): col=q=lane&31, 16 keys/lane
//         (key = (r&3)+8*(r>>2)+4*hl, hl=lane>>5).
//   P repack: C-regs -> B-operand in-register; K-slot sigma(hl*8+e) =
//         (e&3)+8*(e>>2)+4*hl; V A-fragment reads at sigma-permuted offsets
//         (two u16x4 at +4*hl and +8+4*hl). NO Ps LDS, NO 3rd barrier.
//   PV: O^T[64d x 32q] partial over own 32 keys: o = 2 x f32x16 = 32 VGPRs.
// LDS 35328 (Ks 128x68 | Vs 64x140; epilogue overlay Obuf[4][64][33] + Lbuf).
__global__ __launch_bounds__(256, 4) void attn_k(
    const u16* __restrict__ Q, const u16* __restrict__ K,
    const u16* __restrict__ V, u16* __restrict__ O)
{
    __shared__ alignas(16) char lds[35328];
    u16* Ks = (u16*)(lds);                 // [128][68] u16
    u16* Vs = (u16*)(lds + 17408);         // [64][140] u16
    float* Obuf = (float*)(lds);           // [4][64][33] f32 = 33792 B (overlay)
    float* Lbuf = (float*)(lds + 33792);   // [4][32] f32 (overlay)

    const int tid  = threadIdx.x;
    const int wid  = tid >> 6, lane = tid & 63;
    const int hl   = lane >> 5;            // K-slot half selector
    const int lr   = lane & 31;            // row/col within 32
    const int li = blockIdx.x;
    const int bh = li >> 6, qt = li & 63;
    const int b = bh / 12, h = bh - b * 12;
    const int q0 = qt * 32;

    const u16* Qp = Q + ((size_t)b * 2048) * 768 + h * 64;
    const u16* Kp = K + ((size_t)b * 2048) * 768 + h * 64;
    const u16* Vp = V + (size_t)bh * 64 * 2048;
    u16*       Op = O + ((size_t)b * 2048) * 768 + h * 64;

    // Q fragments (B-operand): col=q=lr, k-chunk c: k = 16c + 8*hl + e.
    // Pre-scaled by 1/sqrt(64) = 0.125.
    bf16x8 qf[4];
    #pragma unroll
    for (int c = 0; c < 4; c++) {
        u16x8 t = *(const u16x8*)&Qp[(q0 + lr) * 768 + c*16 + hl*8];
        bf16x8 sc;
        #pragma unroll
        for (int e = 0; e < 8; e++) {
            union { uint32_t u; float f; } z; z.u = ((uint32_t)t[e]) << 16;
            sc[e] = (__bf16)(z.f * 0.125f);
        }
        qf[c] = sc;
    }

    float l_ = 0.f;                 // sum over own keys for q = lr (both hl halves)
    f32x16 o0 = {}, o1 = {};        // O^T partial: d = dh*32+(r&3)+8*(r>>2)+4*hl, q = lr

    const int kr = tid >> 3, kseg = (tid & 7) * 8;
    const int vr = tid >> 4, vseg = (tid & 15) * 8;
    const int kb0 = wid * 32;       // this wave's key slice

    // prefetch tile 0 into registers
    u16x8 kpre[4], vpre[4];
    #pragma unroll
    for (int p = 0; p < 4; p++)
        kpre[p] = *(const u16x8*)&Kp[(kr + p*32)*768 + kseg];
    #pragma unroll
    for (int p = 0; p < 4; p++)
        vpre[p] = *(const u16x8*)&Vp[(vr + p*16)*2048 + vseg];

    for (int kt = 0; kt < 16; kt++) {
        __syncthreads();
        #pragma unroll
        for (int p = 0; p < 4; p++)
            st8(&Ks[(kr + p*32)*68 + kseg], kpre[p]);
        #pragma unroll
        for (int p = 0; p < 4; p++)
            st8(&Vs[(vr + p*16)*140 + vseg], vpre[p]);
        __syncthreads();

        if (kt < 15) {
            #pragma unroll
            for (int p = 0; p < 4; p++)
                kpre[p] = *(const u16x8*)&Kp[((kt+1)*128 + kr + p*32)*768 + kseg];
            #pragma unroll
            for (int p = 0; p < 4; p++)
                vpre[p] = *(const u16x8*)&Vp[(vr + p*16)*2048 + (kt+1)*128 + vseg];
        }

        // S^T: own 32 keys x 32 q, one 32x32 accumulator, K=64 in 4 chunks.
        f32x16 s = {};
        __builtin_amdgcn_s_setprio(1);
        #pragma unroll
        for (int c = 0; c < 4; c++) {
            bf16x8 kf = ld8(&Ks[(kb0 + lr)*68 + c*16 + hl*8]);
            s = __builtin_amdgcn_mfma_f32_32x32x16_bf16(kf, qf[c], s, 0, 0, 0);
        }
        __builtin_amdgcn_s_setprio(0);

        // max-free softmax numerator + per-lane partial sum
        #pragma unroll
        for (int r = 0; r < 16; r++) {
            float p = __expf(s[r]);
            s[r] = p;
            l_ += p;
        }

        // In-register repack: C regs -> two PV B-operand fragments.
        // pb0 = keys {0-3,8-11}+4hl (regs 0..7), pb1 = +16 (regs 8..15).
        union { bf16x8 v; uint32_t w[4]; } pb0, pb1;
        #pragma unroll
        for (int e2 = 0; e2 < 4; e2++) {
            pb0.w[e2] = pk2(s[2*e2],     s[2*e2 + 1]);
            pb1.w[e2] = pk2(s[8 + 2*e2], s[8 + 2*e2 + 1]);
        }

        // O^T += V^T[:, own keys] @ P[own keys, :] ; sigma-permuted V reads.
        const int v4 = kb0 + hl*4;
        {
            bf16x8 va0 = ldvf(&Vs[(0*32 + lr)*140 + v4]);
            bf16x8 va1 = ldvf(&Vs[(0*32 + lr)*140 + v4 + 16]);
            bf16x8 vb0 = ldvf(&Vs[(1*32 + lr)*140 + v4]);
            bf16x8 vb1 = ldvf(&Vs[(1*32 + lr)*140 + v4 + 16]);
            __builtin_amdgcn_s_setprio(1);
            o0 = __builtin_amdgcn_mfma_f32_32x32x16_bf16(va0, pb0.v, o0, 0, 0, 0);
            o0 = __builtin_amdgcn_mfma_f32_32x32x16_bf16(va1, pb1.v, o0, 0, 0, 0);
            o1 = __builtin_amdgcn_mfma_f32_32x32x16_bf16(vb0, pb0.v, o1, 0, 0, 0);
            o1 = __builtin_amdgcn_mfma_f32_32x32x16_bf16(vb1, pb1.v, o1, 0, 0, 0);
            __builtin_amdgcn_s_setprio(0);
        }
    }

    // ---- epilogue: cross-wave reduction over key slices ----
    l_ += __shfl_xor(l_, 32);        // combine hl halves (same q, disjoint keys)
    __syncthreads();                 // all K-loop LDS reads done before overlay
    if (lane < 32)
        Lbuf[wid*32 + lr] = l_;

    #pragma unroll
    for (int r = 0; r < 16; r++) {
        const int dr = (r & 3) + 8*(r >> 2) + 4*hl;
        Obuf[(wid*64 + dr)*33 + lr]      = o0[r];
        Obuf[(wid*64 + 32 + dr)*33 + lr] = o1[r];
    }
    __syncthreads();

    const int q  = tid & 31;         // epilogue q
    const int dblk = tid >> 5;       // d block (0..7), 8 d each
    const float linv = 1.0f / (Lbuf[q] + Lbuf[32 + q] + Lbuf[64 + q] + Lbuf[96 + q]);

    u16x8 ov;
    #pragma unroll
    for (int j = 0; j < 8; j++) {
        const int d = dblk*8 + j;
        const float sum = Obuf[(0*64 + d)*33 + q] + Obuf[(1*64 + d)*33 + q] +
                          Obuf[(2*64 + d)*33 + q] + Obuf[(3*64 + d)*33 + q];
        ov[j] = f2b(sum * linv);
    }
    *(u16x8*)&Op[(size_t)(q0 + q) * 768 + dblk*8] = ov;
}

extern "C" void kernel_launch(void* const* d_in, const int* in_sizes, int n_in,
                              void* d_out, int out_size, void* d_ws, size_t ws_size,
                              hipStream_t stream)
{
    const float* x    = (const float*)d_in[0];   // [2,2048,768] fp32
    const float* wqkv = (const float*)d_in[1];   // [2304,768]   fp32
    const float* bqkv = (const float*)d_in[2];   // [2304]       fp32
    const float* wp   = (const float*)d_in[3];   // [768,768]    fp32
    const float* bp   = (const float*)d_in[4];   // [768]        fp32
    float* out = (float*)d_out;                  // [2,2048,768] fp32
    char* ws = (char*)d_ws;

    // ws: Qw 6.29M | Vt 6.29M | wqkvb 3.54M | wpb 1.18M = 17.3M (proven available)
    // d_out (12.58M fp32): front = Kw bf16 6.29M, back = xb bf16 6.29M; both dead
    // before the proj epilogue overwrites d_out (stream-ordered).
    u16* Qw    = (u16*)(ws);
    u16* Vt    = (u16*)(ws + 6291456);
    u16* wqkvb = (u16*)(ws + 12582912);
    u16* wpb   = (u16*)(ws + 16121856);
    u16* Kw    = (u16*)d_out;
    u16* xb    = (u16*)((char*)d_out + 6291456);

    conv_k<<<512, 256, 0, stream>>>(x, xb, 3145728/4, wqkv, wqkvb, 1769472/4, wp, wpb, 589824/4);
    gemm_qkv<<<dim3(32, 18), 256, 0, stream>>>(xb, wqkvb, bqkv, Qw, Kw, Vt);
    attn_k<<<1536, 256, 0, stream>>>(Qw, Kw, Vt, Qw);
    gemm_proj<<<dim3(64, 12), 256, 0, stream>>>(Qw, wpb, bp, out);
}